// Round 10
// baseline (151.313 us; speedup 1.0000x reference)
//
#include <hip/hip_runtime.h>
#include <math.h>

#define B_ 16
#define D_ 128
#define HH 48
#define WW 48
#define N_ 2304
#define NC 72            // N_/32 row/col chunks of 32
#define SCALE_ 16.0f
#define INV_TEMP 14.285714285714286f
#define L2E_TEMP 20.60992915555662f   // INV_TEMP * log2(e)
#define EPS_ 1e-8f
#define SPLITC 12
#define STAGES 3         // per block: 3 stages x 64 cols = 192 cols = N_/SPLITC

typedef __attribute__((ext_vector_type(8))) short bf16x8;
typedef __attribute__((ext_vector_type(16))) float f32x16;

__device__ __forceinline__ short f2bf(float f) {
    union { float f; unsigned u; } v; v.f = f;
    unsigned r = v.u + 0x7FFFu + ((v.u >> 16) & 1u);
    return (short)(r >> 16);
}

// fragment-major offset (shorts): chunk c (32 rows/cols), k-step ks, lane l, 8 bf16
__device__ __forceinline__ size_t frag_off(int b, int c, int ks, int lane) {
    return ((((size_t)b * NC + c) * 8 + ks) << 9) + (size_t)lane * 8;
}

// async global->LDS, 16B per lane; LDS dest must be wave-uniform base (HW adds lane*16)
__device__ __forceinline__ void gld16(const short* g, short* l) {
    __builtin_amdgcn_global_load_lds(
        (const __attribute__((address_space(1))) void*)g,
        (__attribute__((address_space(3))) void*)l, 16, 0, 0);
}

// ---------------- K0: transpose fb (B,D,N) -> fbT (B,N,D) so the bilinear
// gather's d-axis becomes contiguous (512B runs). Coalesced float4 on both
// global sides; LDS tile [128][68] (pad 68 => 16B-aligned rows, mild conflicts).
__global__ __launch_bounds__(256) void k_tr(const float* __restrict__ fb,
                                            float* __restrict__ fbT) {
    __shared__ float t[128][68];
    const int b = blockIdx.y;
    const int n0 = blockIdx.x * 64;
    const int tid = threadIdx.x;
    const float* src = fb + (size_t)b * D_ * N_;
    float* dst = fbT + (size_t)b * N_ * D_;
    #pragma unroll
    for (int it = 0; it < 8; ++it) {           // load 16 d-rows x 64 n per iter
        const int d = it * 16 + (tid >> 4);
        const int nn = 4 * (tid & 15);
        float4 v = *(const float4*)(src + (size_t)d * N_ + n0 + nn);
        *(float4*)(&t[d][nn]) = v;
    }
    __syncthreads();
    #pragma unroll
    for (int it = 0; it < 8; ++it) {           // store 8 n-rows x 128 d per iter
        const int nn = it * 8 + (tid >> 5);
        const int d = 4 * (tid & 31);
        float4 v = { t[d][nn], t[d + 1][nn], t[d + 2][nn], t[d + 3][nn] };
        *(float4*)(dst + (size_t)(n0 + nn) * D_ + d) = v;
    }
}

// ---------------- K1: warp + normalize -> bf16 fragment-major; transpose-free
// Bilinear gather reads fbT (B,N,D): each corner is 2x float4 per 8-d run.
__global__ __launch_bounds__(256) void k_prep(const float* __restrict__ fa,
                                              const float* __restrict__ fbT,
                                              const float* __restrict__ Ha,
                                              const float* __restrict__ Hb,
                                              const float* __restrict__ Mab,
                                              float* __restrict__ maskA,
                                              short* __restrict__ faF,
                                              short* __restrict__ wbF) {
    __shared__ float part[4][2][32];
    const int b = blockIdx.y;
    const int rb = blockIdx.x;          // 32-pixel chunk (0..71)
    const int n0 = rb * 32;
    const int tid = threadIdx.x;
    const int lane = tid & 63, wv = tid >> 6;
    const int r = lane & 31, h = lane >> 5;
    const int n = n0 + r;

    // per-batch transform T = S_inv @ Hb @ M3 @ inv(Ha) @ S (redundant per thread)
    float T[9];
    {
        const float* A = Ha + b * 9;
        const float* Bm = Hb + b * 9;
        float c00 = A[4] * A[8] - A[5] * A[7];
        float c01 = A[5] * A[6] - A[3] * A[8];
        float c02 = A[3] * A[7] - A[4] * A[6];
        float id = 1.f / (A[0] * c00 + A[1] * c01 + A[2] * c02);
        float inv[9] = { c00 * id, (A[2] * A[7] - A[1] * A[8]) * id, (A[1] * A[5] - A[2] * A[4]) * id,
                         c01 * id, (A[0] * A[8] - A[2] * A[6]) * id, (A[2] * A[3] - A[0] * A[5]) * id,
                         c02 * id, (A[1] * A[6] - A[0] * A[7]) * id, (A[0] * A[4] - A[1] * A[3]) * id };
        float M3[9] = {Mab[0], Mab[1], Mab[2], Mab[3], Mab[4], Mab[5], 0.f, 0.f, 1.f};
        float P1[9], P2[9];
        for (int i = 0; i < 3; ++i)
            for (int j = 0; j < 3; ++j) {
                float s = 0.f;
                for (int k = 0; k < 3; ++k) s += Bm[i * 3 + k] * M3[k * 3 + j];
                P1[i * 3 + j] = s;
            }
        for (int i = 0; i < 3; ++i)
            for (int j = 0; j < 3; ++j) {
                float s = 0.f;
                for (int k = 0; k < 3; ++k) s += P1[i * 3 + k] * inv[k * 3 + j];
                P2[i * 3 + j] = s;
            }
        const float sc[3] = {SCALE_, SCALE_, 1.f};
        for (int i = 0; i < 3; ++i)
            for (int j = 0; j < 3; ++j) T[i * 3 + j] = P2[i * 3 + j] * sc[j] / sc[i];
    }

    const float gx = (float)(n % WW), gy = (float)(n / WW);
    const float X = T[0] * gx + T[1] * gy + T[2];
    const float Y = T[3] * gx + T[4] * gy + T[5];
    const float z = T[6] * gx + T[7] * gy + T[8] + EPS_;
    const float xn = 2.f * (X / z) / (float)(WW - 1) - 1.f;
    const float yn = 2.f * (Y / z) / (float)(HH - 1) - 1.f;
    const float msk = (xn >= -1.f && xn <= 1.f && yn >= -1.f && yn <= 1.f) ? 1.f : 0.f;
    const float ix = (xn + 1.f) * 0.5f * (float)(WW - 1);
    const float iy = (yn + 1.f) * 0.5f * (float)(HH - 1);
    const float x0f = floorf(ix), y0f = floorf(iy);
    const float wx1 = ix - x0f, wx0 = 1.f - wx1;
    const float wy1 = iy - y0f, wy0 = 1.f - wy1;
    const bool vx0 = (x0f >= 0.f) && (x0f <= 47.f);
    const bool vx1 = (x0f + 1.f >= 0.f) && (x0f + 1.f <= 47.f);
    const bool vy0 = (y0f >= 0.f) && (y0f <= 47.f);
    const bool vy1 = (y0f + 1.f >= 0.f) && (y0f + 1.f <= 47.f);
    const float w00 = (vx0 && vy0) ? wx0 * wy0 : 0.f;
    const float w01 = (vx1 && vy0) ? wx1 * wy0 : 0.f;
    const float w10 = (vx0 && vy1) ? wx0 * wy1 : 0.f;
    const float w11 = (vx1 && vy1) ? wx1 * wy1 : 0.f;
    const int x0c = (int)fminf(fmaxf(x0f, 0.f), 47.f);
    const int x1c = (int)fminf(fmaxf(x0f + 1.f, 0.f), 47.f);
    const int y0c = (int)fminf(fmaxf(y0f, 0.f), 47.f);
    const int y1c = (int)fminf(fmaxf(y0f + 1.f, 0.f), 47.f);
    const int o00 = y0c * WW + x0c, o01 = y0c * WW + x1c;
    const int o10 = y1c * WW + x0c, o11 = y1c * WW + x1c;

    const float* fab = fa + (size_t)b * D_ * N_;
    const float* fbtb = fbT + (size_t)b * N_ * D_;
    const float* p00 = fbtb + (size_t)o00 * D_;
    const float* p01 = fbtb + (size_t)o01 * D_;
    const float* p10 = fbtb + (size_t)o10 * D_;
    const float* p11 = fbtb + (size_t)o11 * D_;

    float av[2][8], wvv[2][8];
    float sA = 0.f, sW = 0.f;
    #pragma unroll
    for (int g = 0; g < 2; ++g) {
        const int ks = wv + 4 * g;
        const int dbase = ks * 16 + h * 8;
        // warped-b: 4 corners x 8 contiguous d (2x float4 each)
        float4 c00a = *(const float4*)(p00 + dbase), c00b = *(const float4*)(p00 + dbase + 4);
        float4 c01a = *(const float4*)(p01 + dbase), c01b = *(const float4*)(p01 + dbase + 4);
        float4 c10a = *(const float4*)(p10 + dbase), c10b = *(const float4*)(p10 + dbase + 4);
        float4 c11a = *(const float4*)(p11 + dbase), c11b = *(const float4*)(p11 + dbase + 4);
        float cw[8];
        cw[0] = w00 * c00a.x + w01 * c01a.x + w10 * c10a.x + w11 * c11a.x;
        cw[1] = w00 * c00a.y + w01 * c01a.y + w10 * c10a.y + w11 * c11a.y;
        cw[2] = w00 * c00a.z + w01 * c01a.z + w10 * c10a.z + w11 * c11a.z;
        cw[3] = w00 * c00a.w + w01 * c01a.w + w10 * c10a.w + w11 * c11a.w;
        cw[4] = w00 * c00b.x + w01 * c01b.x + w10 * c10b.x + w11 * c11b.x;
        cw[5] = w00 * c00b.y + w01 * c01b.y + w10 * c10b.y + w11 * c11b.y;
        cw[6] = w00 * c00b.z + w01 * c01b.z + w10 * c10b.z + w11 * c11b.z;
        cw[7] = w00 * c00b.w + w01 * c01b.w + w10 * c10b.w + w11 * c11b.w;
        #pragma unroll
        for (int j = 0; j < 8; ++j) {
            const int d = dbase + j;
            float a = fab[(size_t)d * N_ + n];     // 2x128B segments per wave-load
            av[g][j] = a; wvv[g][j] = cw[j];
            sA += a * a; sW += cw[j] * cw[j];
        }
    }
    // norm: combine h-halves then waves
    sA += __shfl_xor(sA, 32);
    sW += __shfl_xor(sW, 32);
    if (lane < 32) { part[wv][0][r] = sA; part[wv][1][r] = sW; }
    if (tid < 32) maskA[b * N_ + n0 + r] = msk;
    __syncthreads();
    const float rnA = 1.f / fmaxf(sqrtf(part[0][0][r] + part[1][0][r] + part[2][0][r] + part[3][0][r]), 1e-12f);
    const float rnW = 1.f / fmaxf(sqrtf(part[0][1][r] + part[1][1][r] + part[2][1][r] + part[3][1][r]), 1e-12f);

    #pragma unroll
    for (int g = 0; g < 2; ++g) {
        const int ks = wv + 4 * g;
        bf16x8 oa, ow;
        #pragma unroll
        for (int j = 0; j < 8; ++j) {
            oa[j] = f2bf(av[g][j] * rnA);
            ow[j] = f2bf(wvv[g][j] * rnW);
        }
        size_t off = frag_off(b, rb, ks, lane);
        *(bf16x8*)(faF + off) = oa;     // 1KB coalesced store per wave
        *(bf16x8*)(wbF + off) = ow;
    }
}

// ---------------- K2: MFMA logits; round-9 structure (bare v_exp_f32, counted
// vmcnt pipeline, XCD batch-pinning), re-gridded for tail balance:
// SPLITC=12 (192 cols = 3 stages/block) -> grid 3456 = 13.5 blocks/CU, so the
// last dispatch generation wastes 3.7% instead of 16% (1728-grid: 2 generations
// at 1024 slots, second only 69% full).
__global__ __launch_bounds__(256, 4) void k_loss(const short* __restrict__ faF,
                                                 const short* __restrict__ wbF,
                                                 float* __restrict__ Zpart,
                                                 float* __restrict__ dgbuf) {
    __shared__ short bbuf[2][8192];   // 2 x 16 KB stage (64 cols x 128 k bf16, frag-major)
    __shared__ float s_Z[128];
    const int lin = blockIdx.x;
    const int xcd = lin & 7;
    const int i0 = lin >> 3;          // 0..431
    const int b = xcd * 2 + (i0 / 216);
    const int r216 = i0 % 216;
    const int bx = r216 % 18;         // row block: 128 rows (fastest -> shared B panel)
    const int cs = r216 / 18;         // col split: 192 cols (0..11)
    const int tid = threadIdx.x;
    const int lane = tid & 63, w = tid >> 6;
    const int l31 = lane & 31, h = lane >> 5;
    const int rc = bx * 4 + w;        // this wave's 32-row chunk

    bf16x8 af[8];
    #pragma unroll
    for (int ks = 0; ks < 8; ++ks)
        af[ks] = *(const bf16x8*)(faF + frag_off(b, rc, ks, lane));

    float Z[16];
    #pragma unroll
    for (int i = 0; i < 16; ++i) Z[i] = 0.f;

    const short* bsrc = wbF + frag_off(b, cs * 6, 0, 0);   // 6 chunks = 3 stages x 8192 shorts

    // async stage: 16 KB, each wave covers 4 KB in 4 gld16 calls (uniform LDS base)
    #define STAGE_B(nb, s) { \
        const short* sg = bsrc + (size_t)(s) * 8192 + w * 2048 + lane * 8; \
        short* sl = &bbuf[nb][w * 2048]; \
        _Pragma("unroll") \
        for (int j = 0; j < 4; ++j) gld16(sg + j * 512, sl + j * 512); \
    }

    // prologue: 2-deep prefetch; wait only for buf0 (vmcnt(4) leaves buf1's 4 flying)
    STAGE_B(0, 0);
    STAGE_B(1, 1);
    asm volatile("s_waitcnt vmcnt(4)" ::: "memory");
    __builtin_amdgcn_sched_barrier(0);
    __builtin_amdgcn_s_barrier();

    for (int s = 0; s < STAGES; ++s) {
        const short* bb = &bbuf[s & 1][0];
        f32x16 C0, C1;
        #pragma unroll
        for (int i = 0; i < 16; ++i) { C0[i] = 0.f; C1[i] = 0.f; }
        __builtin_amdgcn_s_setprio(1);
        #pragma unroll
        for (int ks = 0; ks < 8; ++ks) {
            bf16x8 b0 = *(const bf16x8*)(bb + ks * 512 + lane * 8);
            bf16x8 b1 = *(const bf16x8*)(bb + 4096 + ks * 512 + lane * 8);
            C0 = __builtin_amdgcn_mfma_f32_32x32x16_bf16(af[ks], b0, C0, 0, 0, 0);
            C1 = __builtin_amdgcn_mfma_f32_32x32x16_bf16(af[ks], b1, C1, 0, 0, 0);
        }
        __builtin_amdgcn_s_setprio(0);
        #pragma unroll
        for (int i = 0; i < 16; ++i) {
            Z[i] += __builtin_amdgcn_exp2f(fmaf(C0[i], L2E_TEMP, -L2E_TEMP))
                  + __builtin_amdgcn_exp2f(fmaf(C1[i], L2E_TEMP, -L2E_TEMP));
        }
        const int jc0 = cs * 6 + 2 * s, jc1 = jc0 + 1;
        if (jc0 == rc) {          // wave-uniform; unique diag owner
            #pragma unroll
            for (int i = 0; i < 16; ++i) {
                int rr = (i & 3) + 8 * (i >> 2) + 4 * h;
                if (l31 == rr) dgbuf[b * N_ + rc * 32 + rr] = INV_TEMP * C0[i];
            }
        }
        if (jc1 == rc) {
            #pragma unroll
            for (int i = 0; i < 16; ++i) {
                int rr = (i & 3) + 8 * (i >> 2) + 4 * h;
                if (l31 == rr) dgbuf[b * N_ + rc * 32 + rr] = INV_TEMP * C1[i];
            }
        }
        // (1) all waves finished reading bbuf[s&1]
        asm volatile("" ::: "memory");
        __builtin_amdgcn_s_barrier();
        // overwrite bbuf[s&1] with stage s+2 (safe: all readers past barrier 1)
        if (s + 2 < STAGES) STAGE_B(s & 1, s + 2);
        if (s + 1 < STAGES) {
            // drain stage s+1's 4 loads; keep s+2's 4 (if any) in flight
            if (s + 2 < STAGES) { asm volatile("s_waitcnt vmcnt(4)" ::: "memory"); }
            else               { asm volatile("s_waitcnt vmcnt(0)" ::: "memory"); }
            __builtin_amdgcn_sched_barrier(0);
        }
        // (2) publish bbuf[(s+1)&1]
        asm volatile("" ::: "memory");
        __builtin_amdgcn_s_barrier();
    }
    #undef STAGE_B

    // reduce Z over 32 column lanes (stays within h-half)
    #pragma unroll
    for (int i = 0; i < 16; ++i) {
        float z = Z[i];
        z += __shfl_xor(z, 1);
        z += __shfl_xor(z, 2);
        z += __shfl_xor(z, 4);
        z += __shfl_xor(z, 8);
        z += __shfl_xor(z, 16);
        if (l31 == 0) {
            int rr = (i & 3) + 8 * (i >> 2) + 4 * h;
            s_Z[w * 32 + rr] = z;
        }
    }
    __syncthreads();
    if (tid < 128)
        Zpart[((size_t)cs * B_ + b) * N_ + bx * 128 + tid] = s_Z[tid];
}

// ---------------- K3: per-row loss + per-block partial sums (no atomics)
__global__ __launch_bounds__(256) void k_pass2(const float* __restrict__ maskA,
                                               const float* __restrict__ Zpart,
                                               const float* __restrict__ dgbuf,
                                               float* __restrict__ partials) {
    const int idx = blockIdx.x * 256 + threadIdx.x;   // B_*N_ = 144*256
    float Zs = 0.f;
    #pragma unroll
    for (int s = 0; s < SPLITC; ++s) Zs += Zpart[(size_t)s * B_ * N_ + idx];
    const float m = maskA[idx];
    float lossv = (logf(Zs) + INV_TEMP - dgbuf[idx]) * m;
    float cm = m;
    for (int off = 1; off < 64; off <<= 1) {
        lossv += __shfl_xor(lossv, off);
        cm += __shfl_xor(cm, off);
    }
    __shared__ float s[8];
    const int wv = threadIdx.x >> 6;
    if ((threadIdx.x & 63) == 0) { s[wv * 2] = lossv; s[wv * 2 + 1] = cm; }
    __syncthreads();
    if (threadIdx.x == 0) {
        partials[blockIdx.x * 2] = s[0] + s[2] + s[4] + s[6];
        partials[blockIdx.x * 2 + 1] = s[1] + s[3] + s[5] + s[7];
    }
}

// ---------------- K4: final reduce of 144 partials
__global__ void k_final(const float* __restrict__ partials, float* __restrict__ out) {
    const int t = threadIdx.x;   // 64 threads
    float tt = 0.f, cc = 0.f;
    for (int i = t; i < 144; i += 64) { tt += partials[i * 2]; cc += partials[i * 2 + 1]; }
    for (int off = 1; off < 64; off <<= 1) {
        tt += __shfl_xor(tt, off);
        cc += __shfl_xor(cc, off);
    }
    if (t == 0) out[0] = (cc > 0.f) ? tt / fmaxf(cc, 1.f) : 0.f;
}

extern "C" void kernel_launch(void* const* d_in, const int* in_sizes, int n_in,
                              void* d_out, int out_size, void* d_ws, size_t ws_size,
                              hipStream_t stream) {
    const float* fa = (const float*)d_in[0];
    const float* fb = (const float*)d_in[1];
    const float* Ha = (const float*)d_in[2];
    const float* Hb = (const float*)d_in[3];
    const float* M = (const float*)d_in[4];
    float* out = (float*)d_out;

    float* wsf = (float*)d_ws;
    float* Zpart = wsf;                                   // SPLITC*B*N (fully written)
    float* dgbuf = Zpart + (size_t)SPLITC * B_ * N_;      // B*N (fully written)
    float* maskA = dgbuf + B_ * N_;                       // B*N
    float* partials = maskA + B_ * N_;                    // 288
    short* faF = (short*)(partials + 512);                // B*NC*8*512 bf16
    short* wbF = faF + (size_t)B_ * NC * 8 * 512;
    float* fbT = (float*)(wbF + (size_t)B_ * NC * 8 * 512);  // B*N*D floats (18.9 MB)

    hipLaunchKernelGGL(k_tr, dim3(N_ / 64, B_), dim3(256), 0, stream, fb, fbT);
    hipLaunchKernelGGL(k_prep, dim3(NC, B_), dim3(256), 0, stream,
                       fa, fbT, Ha, Hb, M, maskA, faF, wbF);
    hipLaunchKernelGGL(k_loss, dim3(8 * 432), dim3(256), 0, stream,
                       faF, wbF, Zpart, dgbuf);
    hipLaunchKernelGGL(k_pass2, dim3(B_ * N_ / 256), dim3(256), 0, stream,
                       maskA, Zpart, dgbuf, partials);
    hipLaunchKernelGGL(k_final, dim3(1), dim3(64), 0, stream, partials, out);
}

// Round 11
// 128.330 us; speedup vs baseline: 1.1791x; 1.1791x over previous
//
#include <hip/hip_runtime.h>
#include <math.h>

#define B_ 16
#define D_ 128
#define HH 48
#define WW 48
#define N_ 2304
#define NC 72            // N_/32 row/col chunks of 32
#define SCALE_ 16.0f
#define INV_TEMP 14.285714285714286f
#define L2E_TEMP 20.60992915555662f   // INV_TEMP * log2(e)
#define EPS_ 1e-8f
#define SPLITC 6
#define STAGES 6         // per block: 6 stages x 64 cols = 384 cols = N_/SPLITC

typedef __attribute__((ext_vector_type(8))) short bf16x8;
typedef __attribute__((ext_vector_type(16))) float f32x16;

__device__ __forceinline__ short f2bf(float f) {
    union { float f; unsigned u; } v; v.f = f;
    unsigned r = v.u + 0x7FFFu + ((v.u >> 16) & 1u);
    return (short)(r >> 16);
}

// fragment-major offset (shorts): chunk c (32 rows/cols), k-step ks, lane l, 8 bf16
__device__ __forceinline__ size_t frag_off(int b, int c, int ks, int lane) {
    return ((((size_t)b * NC + c) * 8 + ks) << 9) + (size_t)lane * 8;
}

// async global->LDS, 16B per lane; LDS dest must be wave-uniform base (HW adds lane*16)
__device__ __forceinline__ void gld16(const short* g, short* l) {
    __builtin_amdgcn_global_load_lds(
        (const __attribute__((address_space(1))) void*)g,
        (__attribute__((address_space(3))) void*)l, 16, 0, 0);
}

// ---------------- K0: transpose fb (B,D,N) -> fbT (B,N,D) so the bilinear
// gather's d-axis becomes contiguous (512B runs). Coalesced float4 on both
// global sides; LDS tile [128][68] (pad 68 => 16B-aligned rows, mild conflicts).
__global__ __launch_bounds__(256) void k_tr(const float* __restrict__ fb,
                                            float* __restrict__ fbT) {
    __shared__ float t[128][68];
    const int b = blockIdx.y;
    const int n0 = blockIdx.x * 64;
    const int tid = threadIdx.x;
    const float* src = fb + (size_t)b * D_ * N_;
    float* dst = fbT + (size_t)b * N_ * D_;
    #pragma unroll
    for (int it = 0; it < 8; ++it) {           // load 16 d-rows x 64 n per iter
        const int d = it * 16 + (tid >> 4);
        const int nn = 4 * (tid & 15);
        float4 v = *(const float4*)(src + (size_t)d * N_ + n0 + nn);
        *(float4*)(&t[d][nn]) = v;
    }
    __syncthreads();
    #pragma unroll
    for (int it = 0; it < 8; ++it) {           // store 8 n-rows x 128 d per iter
        const int nn = it * 8 + (tid >> 5);
        const int d = 4 * (tid & 31);
        float4 v = { t[d][nn], t[d + 1][nn], t[d + 2][nn], t[d + 3][nn] };
        *(float4*)(dst + (size_t)(n0 + nn) * D_ + d) = v;
    }
}

// ---------------- K1: warp + normalize -> bf16 fragment-major; transpose-free
// Bilinear gather reads fbT (B,N,D): each corner is 2x float4 per 8-d run.
__global__ __launch_bounds__(256) void k_prep(const float* __restrict__ fa,
                                              const float* __restrict__ fbT,
                                              const float* __restrict__ Ha,
                                              const float* __restrict__ Hb,
                                              const float* __restrict__ Mab,
                                              float* __restrict__ maskA,
                                              short* __restrict__ faF,
                                              short* __restrict__ wbF) {
    __shared__ float part[4][2][32];
    const int b = blockIdx.y;
    const int rb = blockIdx.x;          // 32-pixel chunk (0..71)
    const int n0 = rb * 32;
    const int tid = threadIdx.x;
    const int lane = tid & 63, wv = tid >> 6;
    const int r = lane & 31, h = lane >> 5;
    const int n = n0 + r;

    // per-batch transform T = S_inv @ Hb @ M3 @ inv(Ha) @ S (redundant per thread)
    float T[9];
    {
        const float* A = Ha + b * 9;
        const float* Bm = Hb + b * 9;
        float c00 = A[4] * A[8] - A[5] * A[7];
        float c01 = A[5] * A[6] - A[3] * A[8];
        float c02 = A[3] * A[7] - A[4] * A[6];
        float id = 1.f / (A[0] * c00 + A[1] * c01 + A[2] * c02);
        float inv[9] = { c00 * id, (A[2] * A[7] - A[1] * A[8]) * id, (A[1] * A[5] - A[2] * A[4]) * id,
                         c01 * id, (A[0] * A[8] - A[2] * A[6]) * id, (A[2] * A[3] - A[0] * A[5]) * id,
                         c02 * id, (A[1] * A[6] - A[0] * A[7]) * id, (A[0] * A[4] - A[1] * A[3]) * id };
        float M3[9] = {Mab[0], Mab[1], Mab[2], Mab[3], Mab[4], Mab[5], 0.f, 0.f, 1.f};
        float P1[9], P2[9];
        for (int i = 0; i < 3; ++i)
            for (int j = 0; j < 3; ++j) {
                float s = 0.f;
                for (int k = 0; k < 3; ++k) s += Bm[i * 3 + k] * M3[k * 3 + j];
                P1[i * 3 + j] = s;
            }
        for (int i = 0; i < 3; ++i)
            for (int j = 0; j < 3; ++j) {
                float s = 0.f;
                for (int k = 0; k < 3; ++k) s += P1[i * 3 + k] * inv[k * 3 + j];
                P2[i * 3 + j] = s;
            }
        const float sc[3] = {SCALE_, SCALE_, 1.f};
        for (int i = 0; i < 3; ++i)
            for (int j = 0; j < 3; ++j) T[i * 3 + j] = P2[i * 3 + j] * sc[j] / sc[i];
    }

    const float gx = (float)(n % WW), gy = (float)(n / WW);
    const float X = T[0] * gx + T[1] * gy + T[2];
    const float Y = T[3] * gx + T[4] * gy + T[5];
    const float z = T[6] * gx + T[7] * gy + T[8] + EPS_;
    const float xn = 2.f * (X / z) / (float)(WW - 1) - 1.f;
    const float yn = 2.f * (Y / z) / (float)(HH - 1) - 1.f;
    const float msk = (xn >= -1.f && xn <= 1.f && yn >= -1.f && yn <= 1.f) ? 1.f : 0.f;
    const float ix = (xn + 1.f) * 0.5f * (float)(WW - 1);
    const float iy = (yn + 1.f) * 0.5f * (float)(HH - 1);
    const float x0f = floorf(ix), y0f = floorf(iy);
    const float wx1 = ix - x0f, wx0 = 1.f - wx1;
    const float wy1 = iy - y0f, wy0 = 1.f - wy1;
    const bool vx0 = (x0f >= 0.f) && (x0f <= 47.f);
    const bool vx1 = (x0f + 1.f >= 0.f) && (x0f + 1.f <= 47.f);
    const bool vy0 = (y0f >= 0.f) && (y0f <= 47.f);
    const bool vy1 = (y0f + 1.f >= 0.f) && (y0f + 1.f <= 47.f);
    const float w00 = (vx0 && vy0) ? wx0 * wy0 : 0.f;
    const float w01 = (vx1 && vy0) ? wx1 * wy0 : 0.f;
    const float w10 = (vx0 && vy1) ? wx0 * wy1 : 0.f;
    const float w11 = (vx1 && vy1) ? wx1 * wy1 : 0.f;
    const int x0c = (int)fminf(fmaxf(x0f, 0.f), 47.f);
    const int x1c = (int)fminf(fmaxf(x0f + 1.f, 0.f), 47.f);
    const int y0c = (int)fminf(fmaxf(y0f, 0.f), 47.f);
    const int y1c = (int)fminf(fmaxf(y0f + 1.f, 0.f), 47.f);
    const int o00 = y0c * WW + x0c, o01 = y0c * WW + x1c;
    const int o10 = y1c * WW + x0c, o11 = y1c * WW + x1c;

    const float* fab = fa + (size_t)b * D_ * N_;
    const float* fbtb = fbT + (size_t)b * N_ * D_;
    const float* p00 = fbtb + (size_t)o00 * D_;
    const float* p01 = fbtb + (size_t)o01 * D_;
    const float* p10 = fbtb + (size_t)o10 * D_;
    const float* p11 = fbtb + (size_t)o11 * D_;

    float av[2][8], wvv[2][8];
    float sA = 0.f, sW = 0.f;
    #pragma unroll
    for (int g = 0; g < 2; ++g) {
        const int ks = wv + 4 * g;
        const int dbase = ks * 16 + h * 8;
        // warped-b: 4 corners x 8 contiguous d (2x float4 each)
        float4 c00a = *(const float4*)(p00 + dbase), c00b = *(const float4*)(p00 + dbase + 4);
        float4 c01a = *(const float4*)(p01 + dbase), c01b = *(const float4*)(p01 + dbase + 4);
        float4 c10a = *(const float4*)(p10 + dbase), c10b = *(const float4*)(p10 + dbase + 4);
        float4 c11a = *(const float4*)(p11 + dbase), c11b = *(const float4*)(p11 + dbase + 4);
        float cw[8];
        cw[0] = w00 * c00a.x + w01 * c01a.x + w10 * c10a.x + w11 * c11a.x;
        cw[1] = w00 * c00a.y + w01 * c01a.y + w10 * c10a.y + w11 * c11a.y;
        cw[2] = w00 * c00a.z + w01 * c01a.z + w10 * c10a.z + w11 * c11a.z;
        cw[3] = w00 * c00a.w + w01 * c01a.w + w10 * c10a.w + w11 * c11a.w;
        cw[4] = w00 * c00b.x + w01 * c01b.x + w10 * c10b.x + w11 * c11b.x;
        cw[5] = w00 * c00b.y + w01 * c01b.y + w10 * c10b.y + w11 * c11b.y;
        cw[6] = w00 * c00b.z + w01 * c01b.z + w10 * c10b.z + w11 * c11b.z;
        cw[7] = w00 * c00b.w + w01 * c01b.w + w10 * c10b.w + w11 * c11b.w;
        #pragma unroll
        for (int j = 0; j < 8; ++j) {
            const int d = dbase + j;
            float a = fab[(size_t)d * N_ + n];     // 2x128B segments per wave-load
            av[g][j] = a; wvv[g][j] = cw[j];
            sA += a * a; sW += cw[j] * cw[j];
        }
    }
    // norm: combine h-halves then waves
    sA += __shfl_xor(sA, 32);
    sW += __shfl_xor(sW, 32);
    if (lane < 32) { part[wv][0][r] = sA; part[wv][1][r] = sW; }
    if (tid < 32) maskA[b * N_ + n0 + r] = msk;
    __syncthreads();
    const float rnA = 1.f / fmaxf(sqrtf(part[0][0][r] + part[1][0][r] + part[2][0][r] + part[3][0][r]), 1e-12f);
    const float rnW = 1.f / fmaxf(sqrtf(part[0][1][r] + part[1][1][r] + part[2][1][r] + part[3][1][r]), 1e-12f);

    #pragma unroll
    for (int g = 0; g < 2; ++g) {
        const int ks = wv + 4 * g;
        bf16x8 oa, ow;
        #pragma unroll
        for (int j = 0; j < 8; ++j) {
            oa[j] = f2bf(av[g][j] * rnA);
            ow[j] = f2bf(wvv[g][j] * rnW);
        }
        size_t off = frag_off(b, rb, ks, lane);
        *(bf16x8*)(faF + off) = oa;     // 1KB coalesced store per wave
        *(bf16x8*)(wbF + off) = ow;
    }
}

// ---------------- K2: MFMA logits; round-9 optimum (reverted verbatim).
// 1 row-chunk/wave, 128-row blocks, SPLITC=6 (384 cols = 6 stages), grid 1728
// = 6.75 blocks/CU streaming into 4-deep residency (~4% tail waste), XCD
// batch-pinning, global_load_lds dbuf, 2-deep counted-vmcnt pipeline, setprio,
// bare v_exp_f32 for the softmax burst (arg in [-42,0], no denormal fixup
// needed; OCML wrapper cost ~7 us -- round-9 win).
__global__ __launch_bounds__(256, 4) void k_loss(const short* __restrict__ faF,
                                                 const short* __restrict__ wbF,
                                                 float* __restrict__ Zpart,
                                                 float* __restrict__ dgbuf) {
    __shared__ short bbuf[2][8192];   // 2 x 16 KB stage (64 cols x 128 k bf16, frag-major)
    __shared__ float s_Z[128];
    const int lin = blockIdx.x;
    const int xcd = lin & 7;
    const int i0 = lin >> 3;          // 0..215
    const int b = xcd * 2 + (i0 / 108);
    const int r108 = i0 % 108;
    const int bx = r108 % 18;         // row block: 128 rows (fastest -> shared B panel)
    const int cs = r108 / 18;         // col split: 384 cols
    const int tid = threadIdx.x;
    const int lane = tid & 63, w = tid >> 6;
    const int l31 = lane & 31, h = lane >> 5;
    const int rc = bx * 4 + w;        // this wave's 32-row chunk

    bf16x8 af[8];
    #pragma unroll
    for (int ks = 0; ks < 8; ++ks)
        af[ks] = *(const bf16x8*)(faF + frag_off(b, rc, ks, lane));

    float Z[16];
    #pragma unroll
    for (int i = 0; i < 16; ++i) Z[i] = 0.f;

    const short* bsrc = wbF + frag_off(b, cs * 12, 0, 0);   // 12 chunks = 6 stages x 8192 shorts

    // async stage: 16 KB, each wave covers 4 KB in 4 gld16 calls (uniform LDS base)
    #define STAGE_B(nb, s) { \
        const short* sg = bsrc + (size_t)(s) * 8192 + w * 2048 + lane * 8; \
        short* sl = &bbuf[nb][w * 2048]; \
        _Pragma("unroll") \
        for (int j = 0; j < 4; ++j) gld16(sg + j * 512, sl + j * 512); \
    }

    // prologue: 2-deep prefetch; wait only for buf0 (vmcnt(4) leaves buf1's 4 flying)
    STAGE_B(0, 0);
    STAGE_B(1, 1);
    asm volatile("s_waitcnt vmcnt(4)" ::: "memory");
    __builtin_amdgcn_sched_barrier(0);
    __builtin_amdgcn_s_barrier();

    for (int s = 0; s < STAGES; ++s) {
        const short* bb = &bbuf[s & 1][0];
        f32x16 C0, C1;
        #pragma unroll
        for (int i = 0; i < 16; ++i) { C0[i] = 0.f; C1[i] = 0.f; }
        __builtin_amdgcn_s_setprio(1);
        #pragma unroll
        for (int ks = 0; ks < 8; ++ks) {
            bf16x8 b0 = *(const bf16x8*)(bb + ks * 512 + lane * 8);
            bf16x8 b1 = *(const bf16x8*)(bb + 4096 + ks * 512 + lane * 8);
            C0 = __builtin_amdgcn_mfma_f32_32x32x16_bf16(af[ks], b0, C0, 0, 0, 0);
            C1 = __builtin_amdgcn_mfma_f32_32x32x16_bf16(af[ks], b1, C1, 0, 0, 0);
        }
        __builtin_amdgcn_s_setprio(0);
        #pragma unroll
        for (int i = 0; i < 16; ++i) {
            Z[i] += __builtin_amdgcn_exp2f(fmaf(C0[i], L2E_TEMP, -L2E_TEMP))
                  + __builtin_amdgcn_exp2f(fmaf(C1[i], L2E_TEMP, -L2E_TEMP));
        }
        const int jc0 = cs * 12 + 2 * s, jc1 = jc0 + 1;
        if (jc0 == rc) {          // wave-uniform; unique diag owner
            #pragma unroll
            for (int i = 0; i < 16; ++i) {
                int rr = (i & 3) + 8 * (i >> 2) + 4 * h;
                if (l31 == rr) dgbuf[b * N_ + rc * 32 + rr] = INV_TEMP * C0[i];
            }
        }
        if (jc1 == rc) {
            #pragma unroll
            for (int i = 0; i < 16; ++i) {
                int rr = (i & 3) + 8 * (i >> 2) + 4 * h;
                if (l31 == rr) dgbuf[b * N_ + rc * 32 + rr] = INV_TEMP * C1[i];
            }
        }
        // (1) all waves finished reading bbuf[s&1]
        asm volatile("" ::: "memory");
        __builtin_amdgcn_s_barrier();
        // overwrite bbuf[s&1] with stage s+2 (safe: all readers past barrier 1)
        if (s + 2 < STAGES) STAGE_B(s & 1, s + 2);
        if (s + 1 < STAGES) {
            // drain stage s+1's 4 loads; keep s+2's 4 (if any) in flight
            if (s + 2 < STAGES) { asm volatile("s_waitcnt vmcnt(4)" ::: "memory"); }
            else               { asm volatile("s_waitcnt vmcnt(0)" ::: "memory"); }
            __builtin_amdgcn_sched_barrier(0);
        }
        // (2) publish bbuf[(s+1)&1]
        asm volatile("" ::: "memory");
        __builtin_amdgcn_s_barrier();
    }
    #undef STAGE_B

    // reduce Z over 32 column lanes (stays within h-half)
    #pragma unroll
    for (int i = 0; i < 16; ++i) {
        float z = Z[i];
        z += __shfl_xor(z, 1);
        z += __shfl_xor(z, 2);
        z += __shfl_xor(z, 4);
        z += __shfl_xor(z, 8);
        z += __shfl_xor(z, 16);
        if (l31 == 0) {
            int rr = (i & 3) + 8 * (i >> 2) + 4 * h;
            s_Z[w * 32 + rr] = z;
        }
    }
    __syncthreads();
    if (tid < 128)
        Zpart[((size_t)cs * B_ + b) * N_ + bx * 128 + tid] = s_Z[tid];
}

// ---------------- K3: per-row loss + per-block partial sums (no atomics)
__global__ __launch_bounds__(256) void k_pass2(const float* __restrict__ maskA,
                                               const float* __restrict__ Zpart,
                                               const float* __restrict__ dgbuf,
                                               float* __restrict__ partials) {
    const int idx = blockIdx.x * 256 + threadIdx.x;   // B_*N_ = 144*256
    float Zs = 0.f;
    #pragma unroll
    for (int s = 0; s < SPLITC; ++s) Zs += Zpart[(size_t)s * B_ * N_ + idx];
    const float m = maskA[idx];
    float lossv = (logf(Zs) + INV_TEMP - dgbuf[idx]) * m;
    float cm = m;
    for (int off = 1; off < 64; off <<= 1) {
        lossv += __shfl_xor(lossv, off);
        cm += __shfl_xor(cm, off);
    }
    __shared__ float s[8];
    const int wv = threadIdx.x >> 6;
    if ((threadIdx.x & 63) == 0) { s[wv * 2] = lossv; s[wv * 2 + 1] = cm; }
    __syncthreads();
    if (threadIdx.x == 0) {
        partials[blockIdx.x * 2] = s[0] + s[2] + s[4] + s[6];
        partials[blockIdx.x * 2 + 1] = s[1] + s[3] + s[5] + s[7];
    }
}

// ---------------- K4: final reduce of 144 partials
__global__ void k_final(const float* __restrict__ partials, float* __restrict__ out) {
    const int t = threadIdx.x;   // 64 threads
    float tt = 0.f, cc = 0.f;
    for (int i = t; i < 144; i += 64) { tt += partials[i * 2]; cc += partials[i * 2 + 1]; }
    for (int off = 1; off < 64; off <<= 1) {
        tt += __shfl_xor(tt, off);
        cc += __shfl_xor(cc, off);
    }
    if (t == 0) out[0] = (cc > 0.f) ? tt / fmaxf(cc, 1.f) : 0.f;
}

extern "C" void kernel_launch(void* const* d_in, const int* in_sizes, int n_in,
                              void* d_out, int out_size, void* d_ws, size_t ws_size,
                              hipStream_t stream) {
    const float* fa = (const float*)d_in[0];
    const float* fb = (const float*)d_in[1];
    const float* Ha = (const float*)d_in[2];
    const float* Hb = (const float*)d_in[3];
    const float* M = (const float*)d_in[4];
    float* out = (float*)d_out;

    float* wsf = (float*)d_ws;
    float* Zpart = wsf;                                   // SPLITC*B*N (fully written)
    float* dgbuf = Zpart + (size_t)SPLITC * B_ * N_;      // B*N (fully written)
    float* maskA = dgbuf + B_ * N_;                       // B*N
    float* partials = maskA + B_ * N_;                    // 288
    short* faF = (short*)(partials + 512);                // B*NC*8*512 bf16
    short* wbF = faF + (size_t)B_ * NC * 8 * 512;
    float* fbT = (float*)(wbF + (size_t)B_ * NC * 8 * 512);  // B*N*D floats (18.9 MB)

    hipLaunchKernelGGL(k_tr, dim3(N_ / 64, B_), dim3(256), 0, stream, fb, fbT);
    hipLaunchKernelGGL(k_prep, dim3(NC, B_), dim3(256), 0, stream,
                       fa, fbT, Ha, Hb, M, maskA, faF, wbF);
    hipLaunchKernelGGL(k_loss, dim3(8 * 216), dim3(256), 0, stream,
                       faF, wbF, Zpart, dgbuf);
    hipLaunchKernelGGL(k_pass2, dim3(B_ * N_ / 256), dim3(256), 0, stream,
                       maskA, Zpart, dgbuf, partials);
    hipLaunchKernelGGL(k_final, dim3(1), dim3(64), 0, stream, partials, out);
}